// Round 1
// baseline (81.308 us; speedup 1.0000x reference)
//
#include <hip/hip_runtime.h>
#include <math.h>

#define GROUPS 10
#define INPUTS 6
#define COLS (GROUPS * INPUTS)   // 60
#define EPSV 1e-4f
#define NB1 2048                  // blocks for main pass
#define NT 256                    // threads per block

// ---------------------------------------------------------------------------
// K1: grouped matmul y = x . W^T + b, optional store of y, per-block partial
// sums of y and y^2 per group. Deterministic (no atomics).
// ---------------------------------------------------------------------------
template <bool STORE_Y>
__global__ __launch_bounds__(NT) void k1_compute(
    const float* __restrict__ in,      // [B, 60]
    const float* __restrict__ Wp,      // [10, 6]
    const float* __restrict__ bp,      // [10]
    float* __restrict__ y_out,         // [B, 10] (ws) — only if STORE_Y
    float* __restrict__ partials,      // [gridDim.x, 20]
    int B)
{
    const int tid = threadIdx.x;
    const int gid = blockIdx.x * NT + tid;
    const int stride = gridDim.x * NT;

    // W, b: wave-uniform addresses with constant offsets -> scalar loads
    float Wr[COLS];
#pragma unroll
    for (int j = 0; j < COLS; ++j) Wr[j] = Wp[j];
    float br[GROUPS];
#pragma unroll
    for (int g = 0; g < GROUPS; ++g) br[g] = bp[g];

    float s[GROUPS], sq[GROUPS];
#pragma unroll
    for (int g = 0; g < GROUPS; ++g) { s[g] = 0.f; sq[g] = 0.f; }

    for (int r = gid; r < B; r += stride) {
        const float4* row4 = reinterpret_cast<const float4*>(in + (size_t)r * COLS);
        float4 v[15];
#pragma unroll
        for (int j = 0; j < 15; ++j) v[j] = row4[j];
        const float* x = reinterpret_cast<const float*>(v);

        float y[GROUPS];
#pragma unroll
        for (int g = 0; g < GROUPS; ++g) {
            float acc = br[g];
#pragma unroll
            for (int i = 0; i < INPUTS; ++i)
                acc = fmaf(x[g * INPUTS + i], Wr[g * INPUTS + i], acc);
            y[g] = acc;
            s[g] += acc;
            sq[g] = fmaf(acc, acc, sq[g]);
        }

        if (STORE_Y) {
            float2* yo = reinterpret_cast<float2*>(y_out + (size_t)r * GROUPS);
#pragma unroll
            for (int j = 0; j < 5; ++j) yo[j] = make_float2(y[2 * j], y[2 * j + 1]);
        }
    }

    // 64-lane wave reduction
#pragma unroll
    for (int off = 32; off > 0; off >>= 1) {
#pragma unroll
        for (int g = 0; g < GROUPS; ++g) {
            s[g]  += __shfl_down(s[g],  off, 64);
            sq[g] += __shfl_down(sq[g], off, 64);
        }
    }

    __shared__ float ls[NT / 64][2 * GROUPS];
    const int lane = tid & 63;
    const int wid  = tid >> 6;
    if (lane == 0) {
#pragma unroll
        for (int g = 0; g < GROUPS; ++g) {
            ls[wid][g]          = s[g];
            ls[wid][GROUPS + g] = sq[g];
        }
    }
    __syncthreads();
    if (tid < 2 * GROUPS) {
        float t = ls[0][tid] + ls[1][tid] + ls[2][tid] + ls[3][tid];
        partials[(size_t)blockIdx.x * (2 * GROUPS) + tid] = t;
    }
}

// ---------------------------------------------------------------------------
// K2: reduce per-block partials -> scale/shift per group. Single block.
// ss[0..9] = gamma*rsqrt(var+eps); ss[10..19] = beta - mean*scale
// ---------------------------------------------------------------------------
__global__ __launch_bounds__(NT) void k2_finalize(
    const float* __restrict__ partials, int nblocks,
    const float* __restrict__ gamma, const float* __restrict__ beta,
    float* __restrict__ ss, float invB)
{
    const int tid = threadIdx.x;
    float acc[2 * GROUPS];
#pragma unroll
    for (int j = 0; j < 2 * GROUPS; ++j) acc[j] = 0.f;

    for (int blk = tid; blk < nblocks; blk += NT) {
#pragma unroll
        for (int j = 0; j < 2 * GROUPS; ++j)
            acc[j] += partials[(size_t)blk * (2 * GROUPS) + j];
    }

#pragma unroll
    for (int off = 32; off > 0; off >>= 1) {
#pragma unroll
        for (int j = 0; j < 2 * GROUPS; ++j)
            acc[j] += __shfl_down(acc[j], off, 64);
    }

    __shared__ float ls[NT / 64][2 * GROUPS];
    const int lane = tid & 63;
    const int wid  = tid >> 6;
    if (lane == 0) {
#pragma unroll
        for (int j = 0; j < 2 * GROUPS; ++j) ls[wid][j] = acc[j];
    }
    __syncthreads();
    if (tid < GROUPS) {
        float sum  = ls[0][tid] + ls[1][tid] + ls[2][tid] + ls[3][tid];
        float sumq = ls[0][GROUPS + tid] + ls[1][GROUPS + tid] +
                     ls[2][GROUPS + tid] + ls[3][GROUPS + tid];
        float mean = sum * invB;
        float var  = sumq * invB - mean * mean;   // biased variance
        float sc   = gamma[tid] * rsqrtf(var + EPSV);
        ss[tid]          = sc;
        ss[GROUPS + tid] = beta[tid] - mean * sc;
    }
}

// ---------------------------------------------------------------------------
// K3: normalize stored y -> out.  n4 = B*GROUPS/4 (divisible for even B).
// ---------------------------------------------------------------------------
__global__ __launch_bounds__(NT) void k3_normalize(
    const float4* __restrict__ y4,
    const float* __restrict__ ss,
    float4* __restrict__ out4, int n4)
{
    __shared__ float sc[GROUPS], sh[GROUPS];
    if (threadIdx.x < GROUPS) {
        sc[threadIdx.x] = ss[threadIdx.x];
        sh[threadIdx.x] = ss[GROUPS + threadIdx.x];
    }
    __syncthreads();

    int gid = blockIdx.x * NT + threadIdx.x;
    int stride = gridDim.x * NT;
    for (int q = gid; q < n4; q += stride) {
        float4 v = y4[q];
        int e = (q * 4) % GROUPS;          // group of element 0
        int g0 = e;
        int g1 = g0 + 1; if (g1 >= GROUPS) g1 -= GROUPS;
        int g2 = g1 + 1; if (g2 >= GROUPS) g2 -= GROUPS;
        int g3 = g2 + 1; if (g3 >= GROUPS) g3 -= GROUPS;
        v.x = fmaf(v.x, sc[g0], sh[g0]);
        v.y = fmaf(v.y, sc[g1], sh[g1]);
        v.z = fmaf(v.z, sc[g2], sh[g2]);
        v.w = fmaf(v.w, sc[g3], sh[g3]);
        out4[q] = v;
    }
}

// ---------------------------------------------------------------------------
// K3b (fallback, ws too small to hold y): recompute y from input, normalize.
// ---------------------------------------------------------------------------
__global__ __launch_bounds__(NT) void k3_recompute(
    const float* __restrict__ in,
    const float* __restrict__ Wp,
    const float* __restrict__ bp,
    const float* __restrict__ ss,
    float* __restrict__ out, int B)
{
    const int tid = threadIdx.x;
    const int gid = blockIdx.x * NT + tid;
    const int stride = gridDim.x * NT;

    float Wr[COLS];
#pragma unroll
    for (int j = 0; j < COLS; ++j) Wr[j] = Wp[j];
    float br[GROUPS];
#pragma unroll
    for (int g = 0; g < GROUPS; ++g) br[g] = bp[g];
    float scr[GROUPS], shr[GROUPS];
#pragma unroll
    for (int g = 0; g < GROUPS; ++g) { scr[g] = ss[g]; shr[g] = ss[GROUPS + g]; }

    for (int r = gid; r < B; r += stride) {
        const float4* row4 = reinterpret_cast<const float4*>(in + (size_t)r * COLS);
        float4 v[15];
#pragma unroll
        for (int j = 0; j < 15; ++j) v[j] = row4[j];
        const float* x = reinterpret_cast<const float*>(v);
        float y[GROUPS];
#pragma unroll
        for (int g = 0; g < GROUPS; ++g) {
            float acc = br[g];
#pragma unroll
            for (int i = 0; i < INPUTS; ++i)
                acc = fmaf(x[g * INPUTS + i], Wr[g * INPUTS + i], acc);
            y[g] = fmaf(acc, scr[g], shr[g]);
        }
        float2* yo = reinterpret_cast<float2*>(out + (size_t)r * GROUPS);
#pragma unroll
        for (int j = 0; j < 5; ++j) yo[j] = make_float2(y[2 * j], y[2 * j + 1]);
    }
}

extern "C" void kernel_launch(void* const* d_in, const int* in_sizes, int n_in,
                              void* d_out, int out_size, void* d_ws, size_t ws_size,
                              hipStream_t stream)
{
    const float* in    = (const float*)d_in[0];
    const float* W     = (const float*)d_in[1];
    const float* bias  = (const float*)d_in[2];
    const float* gamma = (const float*)d_in[3];
    const float* beta  = (const float*)d_in[4];
    float* out = (float*)d_out;

    const int B = in_sizes[0] / COLS;      // 1048576
    float* ws = (float*)d_ws;

    const size_t yFloats    = (size_t)B * GROUPS;
    const size_t partFloats = (size_t)NB1 * 2 * GROUPS;
    const size_t needStore  = (yFloats + partFloats + 2 * GROUPS) * sizeof(float);

    if (ws_size >= needStore && ((size_t)B * GROUPS) % 4 == 0) {
        float* y_ws     = ws;
        float* partials = ws + yFloats;
        float* ss       = partials + partFloats;
        k1_compute<true><<<NB1, NT, 0, stream>>>(in, W, bias, y_ws, partials, B);
        k2_finalize<<<1, NT, 0, stream>>>(partials, NB1, gamma, beta, ss, 1.0f / (float)B);
        const int n4 = (B * GROUPS) / 4;
        k3_normalize<<<2048, NT, 0, stream>>>((const float4*)y_ws, ss, (float4*)out, n4);
    } else {
        float* partials = ws;
        float* ss       = partials + partFloats;
        k1_compute<false><<<NB1, NT, 0, stream>>>(in, W, bias, nullptr, partials, B);
        k2_finalize<<<1, NT, 0, stream>>>(partials, NB1, gamma, beta, ss, 1.0f / (float)B);
        k3_recompute<<<NB1, NT, 0, stream>>>(in, W, bias, ss, out, B);
    }
}